// Round 3
// baseline (225.122 us; speedup 1.0000x reference)
//
#include <hip/hip_runtime.h>

// Problem geometry
#define BATCH 4
#define CIN   8
#define DEPTH 48
#define HGT   128
#define WID   160

#define HW    (HGT*WID)        // 20480
#define DHW   (DEPTH*HW)       // 983040
#define CDHW  (CIN*DHW)        // 7864320 (elements per batch sample)
#define NPIX  (BATCH*HW)       // 81920

#define DSPLIT 8
#define DCHUNK (DEPTH/DSPLIT)  // 6
#define TILES_PER_B (HW/128)   // 160 (128 px per 1-wave tile, 2 px/lane)
#define NTILES (NPIX/128)      // 640

// ws layout (dword offsets) — all f32 folded weights
#define WS_W0F 0     // 128
#define WS_S0F 128   // 16
#define WS_W1F 144   // 128
#define WS_S1F 272   // 8
#define WS_W2F 280   // 8
#define WS_B2F 288   // 1
#define WS_FLAG 384  // uint: 1 = tensors are bf16, 0 = fp32
#define WS_PART 512  // DSPLIT*NPIX f32 partial maxima

static __device__ __forceinline__ float asf(unsigned int u) {
    return __builtin_bit_cast(float, u);
}
static __device__ __forceinline__ unsigned int asu(float f) {
    return __builtin_bit_cast(unsigned int, f);
}
// dtype-agnostic scalar param load (bf16 via shift, else fp32)
static __device__ __forceinline__ float ldp(const void* p, int i, bool bf) {
    if (bf) {
        unsigned int u = ((const unsigned short*)p)[i];
        return asf(u << 16);
    }
    return ((const float*)p)[i];
}

// ---------------- detect: decide bf16 vs fp32 from x's bit patterns ----------------
__global__ void detect_kernel(const unsigned int* __restrict__ x, unsigned int* __restrict__ wsu)
{
    int lane = threadIdx.x;
    int cnt = 0;
    // sample 16 dwords per lane, scattered; max index < 15728640 (bf16 dword count)
    #pragma unroll
    for (int i = 0; i < 16; ++i) {
        unsigned int v = x[(unsigned)(lane * 997 + i * 61440 + 12345)];
        unsigned int b1 = (v >> 8) & 0xFFu;          // byte1: bf16 exponent byte vs fp32 mantissa
        if ((b1 & 0x78u) == 0x38u) ++cnt;            // |v| in [2^-15, 2): ~95% bf16, ~6% fp32
    }
    #pragma unroll
    for (int off = 32; off > 0; off >>= 1) cnt += __shfl_down(cnt, off, 64);
    if (lane == 0) wsu[WS_FLAG] = (cnt >= 512) ? 1u : 0u;
}

// ---------------- prep: fold BN into conv weights (fp32) ----------------
__global__ void prep_kernel(const void* __restrict__ w0, const void* __restrict__ g0,
                            const void* __restrict__ b0, const void* __restrict__ m0,
                            const void* __restrict__ v0, const void* __restrict__ w1,
                            const void* __restrict__ g1, const void* __restrict__ b1,
                            const void* __restrict__ m1, const void* __restrict__ v1,
                            const void* __restrict__ w2, const void* __restrict__ b2,
                            float* __restrict__ ws)
{
    bool bf = (((const unsigned int*)ws)[WS_FLAG] != 0u);
    int t = threadIdx.x;
    if (t < 16) {
        float sc = ldp(g0, t, bf) * rsqrtf(ldp(v0, t, bf) + 1e-5f);
        for (int c = 0; c < 8; ++c)
            ws[WS_W0F + t*8 + c] = ldp(w0, t*8 + c, bf) * sc;
        ws[WS_S0F + t] = ldp(b0, t, bf) - ldp(m0, t, bf) * sc;
    }
    if (t < 8) {
        float sc = ldp(g1, t, bf) * rsqrtf(ldp(v1, t, bf) + 1e-5f);
        for (int c = 0; c < 16; ++c)
            ws[WS_W1F + t*16 + c] = ldp(w1, t*16 + c, bf) * sc;
        ws[WS_S1F + t] = ldp(b1, t, bf) - ldp(m1, t, bf) * sc;
        ws[WS_W2F + t] = ldp(w2, t, bf);
    }
    if (t == 0) ws[WS_B2F] = ldp(b2, 0, bf);
}

// ---------------- main: stream x, fused 3-layer MLP per point, max over depth chunk ----------------
__global__ __launch_bounds__(64, 1) void main_kernel(const void* __restrict__ xv,
                                                     const float* __restrict__ ws,
                                                     float* __restrict__ part)
{
    bool bf = (((const unsigned int*)ws)[WS_FLAG] != 0u);
    const unsigned int* xb = (const unsigned int*)xv;  // bf16 view: dword = 2 adjacent px of one channel
    const float2*      xf = (const float2*)xv;         // fp32 view: float2 = 2 adjacent px

    int lane = threadIdx.x;
    int bid  = blockIdx.x;
    int tile = bid % NTILES;
    int dc   = bid / NTILES;
    int b    = tile / TILES_PER_B;
    int hwp  = (tile % TILES_PER_B) * 64 + lane;       // pixel-pair index within image
    unsigned bbase = (unsigned)(b * (CDHW/2)) + (unsigned)hwp;   // pair-index base (same for both views)
    int d0 = dc * DCHUNK;

    // preload folded fp32 weights into VGPRs
    float W0f[128], S0[16], W1f[128], S1[8], W2[8];
    {
        const float4* q0 = (const float4*)(ws + WS_W0F);
        #pragma unroll
        for (int i = 0; i < 32; ++i) { float4 f = q0[i]; W0f[4*i]=f.x; W0f[4*i+1]=f.y; W0f[4*i+2]=f.z; W0f[4*i+3]=f.w; }
        const float4* qs = (const float4*)(ws + WS_S0F);
        #pragma unroll
        for (int i = 0; i < 4; ++i) { float4 f = qs[i]; S0[4*i]=f.x; S0[4*i+1]=f.y; S0[4*i+2]=f.z; S0[4*i+3]=f.w; }
        const float4* q1 = (const float4*)(ws + WS_W1F);
        #pragma unroll
        for (int i = 0; i < 32; ++i) { float4 f = q1[i]; W1f[4*i]=f.x; W1f[4*i+1]=f.y; W1f[4*i+2]=f.z; W1f[4*i+3]=f.w; }
        const float4* qt = (const float4*)(ws + WS_S1F);
        #pragma unroll
        for (int i = 0; i < 2; ++i) { float4 f = qt[i]; S1[4*i]=f.x; S1[4*i+1]=f.y; S1[4*i+2]=f.z; S1[4*i+3]=f.w; }
        const float4* qw = (const float4*)(ws + WS_W2F);
        #pragma unroll
        for (int i = 0; i < 2; ++i) { float4 f = qw[i]; W2[4*i]=f.x; W2[4*i+1]=f.y; W2[4*i+2]=f.z; W2[4*i+3]=f.w; }
    }
    float B2v = ws[WS_B2F];

    float mA = -1e30f, mB = -1e30f;

    for (int dd = 0; dd < DCHUNK; ++dd) {
        int d = d0 + dd;
        unsigned idx0 = bbase + (unsigned)(d * (HW/2));

        float xAf[8], xBf[8];   // channel values for the even / odd pixel
        if (bf) {
            #pragma unroll
            for (int c = 0; c < 8; ++c) {
                unsigned int v = xb[idx0 + (unsigned)(c * (DHW/2))];
                xAf[c] = asf(v << 16);
                xBf[c] = asf(v & 0xFFFF0000u);
            }
        } else {
            #pragma unroll
            for (int c = 0; c < 8; ++c) {
                float2 v = xf[idx0 + (unsigned)(c * (DHW/2))];
                xAf[c] = v.x;
                xBf[c] = v.y;
            }
        }

        // layer 0: 8 -> 16, folded bias, relu
        float h0A[16], h0B[16];
        #pragma unroll
        for (int o = 0; o < 16; ++o) {
            float a = S0[o], bb = S0[o];
            #pragma unroll
            for (int c = 0; c < 8; ++c) {
                a  = fmaf(xAf[c], W0f[o*8 + c], a);
                bb = fmaf(xBf[c], W0f[o*8 + c], bb);
            }
            h0A[o] = fmaxf(a, 0.f);
            h0B[o] = fmaxf(bb, 0.f);
        }

        // layer 1: 16 -> 8 (+relu), layer 2: 8 -> 1 fused
        float sA = B2v, sB = B2v;
        #pragma unroll
        for (int o = 0; o < 8; ++o) {
            float a = S1[o], bb = S1[o];
            #pragma unroll
            for (int c = 0; c < 16; ++c) {
                a  = fmaf(h0A[c], W1f[o*16 + c], a);
                bb = fmaf(h0B[c], W1f[o*16 + c], bb);
            }
            sA = fmaf(W2[o], fmaxf(a, 0.f), sA);
            sB = fmaf(W2[o], fmaxf(bb, 0.f), sB);
        }
        mA = fmaxf(mA, sA);
        mB = fmaxf(mB, sB);
    }

    float2 r; r.x = mA; r.y = mB;
    float2* pp = (float2*)(part + (size_t)dc * NPIX + (size_t)b * HW);
    pp[hwp] = r;   // coalesced 8 B/lane
}

// ---------------- reduce: max over depth chunks, sigmoid, dtype-correct store ----------------
__global__ __launch_bounds__(256) void reduce_kernel(const float* __restrict__ part,
                                                     const float* __restrict__ ws,
                                                     void* __restrict__ out)
{
    bool bf = (((const unsigned int*)ws)[WS_FLAG] != 0u);
    int px = blockIdx.x * 256 + threadIdx.x;
    float m = part[px];
    #pragma unroll
    for (int k = 1; k < DSPLIT; ++k) m = fmaxf(m, part[(size_t)k * NPIX + px]);
    float sg = 1.0f / (1.0f + __expf(-m));   // sigmoid(max) == max(sigmoid): monotone
    if (bf) {
        unsigned int u = asu(sg);
        unsigned int r = (u + 0x7FFFu + ((u >> 16) & 1u)) >> 16;   // RNE bf16 (sg > 0, no NaN)
        ((unsigned short*)out)[px] = (unsigned short)r;
    } else {
        ((float*)out)[px] = sg;
    }
}

extern "C" void kernel_launch(void* const* d_in, const int* in_sizes, int n_in,
                              void* d_out, int out_size, void* d_ws, size_t ws_size,
                              hipStream_t stream)
{
    float* ws = (float*)d_ws;

    detect_kernel<<<1, 64, 0, stream>>>((const unsigned int*)d_in[0], (unsigned int*)d_ws);

    prep_kernel<<<1, 64, 0, stream>>>(
        d_in[1], d_in[2], d_in[3], d_in[4], d_in[5], d_in[6],
        d_in[7], d_in[8], d_in[9], d_in[10], d_in[11], d_in[12], ws);

    main_kernel<<<NTILES * DSPLIT, 64, 0, stream>>>(d_in[0], ws, ws + WS_PART);

    reduce_kernel<<<NPIX / 256, 256, 0, stream>>>(ws + WS_PART, ws, d_out);
}

// Round 4
// 219.537 us; speedup vs baseline: 1.0254x; 1.0254x over previous
//
#include <hip/hip_runtime.h>

// Problem geometry
#define BATCH 4
#define CIN   8
#define DEPTH 48
#define HGT   128
#define WID   160

#define HW    (HGT*WID)        // 20480
#define DHW   (DEPTH*HW)       // 983040
#define CDHW  (CIN*DHW)        // 7864320 (elements per batch sample)
#define NPIX  (BATCH*HW)       // 81920

#define DSPLIT 8
#define DCHUNK (DEPTH/DSPLIT)  // 6
#define TILES_PER_B (HW/128)   // 160 (128 px per 1-wave tile, 2 px/lane)
#define NTILES (NPIX/128)      // 640

// ws layout (dword offsets)
#define WS_W0P 0     // 64 uints: f16x2 pairs, layer0 (16 o x 4 cpairs)
#define WS_S0F 64    // 16 f32 folded biases
#define WS_W1P 80    // 64 uints: f16x2 pairs, layer1 (8 o x 8 cpairs)
#define WS_S1F 144   // 8 f32
#define WS_W2F 152   // 8 f32
#define WS_B2F 160   // 1 f32
#define WS_FLAG 384  // uint: 1 = tensors are bf16, 0 = fp32
#define WS_PART 512  // DSPLIT*NPIX f32 partial maxima

typedef _Float16 half2_t __attribute__((ext_vector_type(2)));   // fdot2 operand type

static __device__ __forceinline__ float asf(unsigned int u) {
    return __builtin_bit_cast(float, u);
}
static __device__ __forceinline__ unsigned int asu(float f) {
    return __builtin_bit_cast(unsigned int, f);
}
static __device__ __forceinline__ unsigned int pkrtz_u(float a, float b) {
    return __builtin_bit_cast(unsigned int, __builtin_amdgcn_cvt_pkrtz(a, b));
}
static __device__ __forceinline__ float fdot2_u(unsigned int a, unsigned int b, float c) {
    return __builtin_amdgcn_fdot2(__builtin_bit_cast(half2_t, a),
                                  __builtin_bit_cast(half2_t, b), c, false);
}
// dtype-agnostic scalar param load (bf16 via shift, else fp32)
static __device__ __forceinline__ float ldp(const void* p, int i, bool bf) {
    if (bf) {
        unsigned int u = ((const unsigned short*)p)[i];
        return asf(u << 16);
    }
    return ((const float*)p)[i];
}

// ---------------- prep: detect dtype, fold BN, pack weights to f16 pairs ----------------
__global__ void prep_kernel(const unsigned int* __restrict__ x,
                            const void* __restrict__ w0, const void* __restrict__ g0,
                            const void* __restrict__ b0, const void* __restrict__ m0,
                            const void* __restrict__ v0, const void* __restrict__ w1,
                            const void* __restrict__ g1, const void* __restrict__ b1,
                            const void* __restrict__ m1, const void* __restrict__ v1,
                            const void* __restrict__ w2, const void* __restrict__ b2,
                            float* __restrict__ ws)
{
    unsigned int* wsu = (unsigned int*)ws;
    int t = threadIdx.x;

    // dtype detect: byte-1 of a dword is the bf16 exponent byte (hit ~95%) vs fp32 mantissa (~6%)
    int cnt = 0;
    #pragma unroll
    for (int i = 0; i < 16; ++i) {
        unsigned int v = x[(unsigned)(t * 997 + i * 61440 + 12345)];  // max idx < 1M, safe both dtypes
        if ((((v >> 8) & 0x78u)) == 0x38u) ++cnt;                     // |v| in [2^-15, 2)
    }
    #pragma unroll
    for (int off = 32; off > 0; off >>= 1) cnt += __shfl_down(cnt, off, 64);
    cnt = __shfl(cnt, 0, 64);                 // broadcast total (1024 samples)
    bool bf = (cnt >= 512);
    if (t == 0) wsu[WS_FLAG] = bf ? 1u : 0u;

    if (t < 16) {
        float sc = ldp(g0, t, bf) * rsqrtf(ldp(v0, t, bf) + 1e-5f);
        for (int c = 0; c < 4; ++c)
            wsu[WS_W0P + t*4 + c] = pkrtz_u(ldp(w0, t*8 + 2*c, bf) * sc,
                                            ldp(w0, t*8 + 2*c + 1, bf) * sc);
        ws[WS_S0F + t] = ldp(b0, t, bf) - ldp(m0, t, bf) * sc;
    }
    if (t < 8) {
        float sc = ldp(g1, t, bf) * rsqrtf(ldp(v1, t, bf) + 1e-5f);
        for (int c = 0; c < 8; ++c)
            wsu[WS_W1P + t*8 + c] = pkrtz_u(ldp(w1, t*16 + 2*c, bf) * sc,
                                            ldp(w1, t*16 + 2*c + 1, bf) * sc);
        ws[WS_S1F + t] = ldp(b1, t, bf) - ldp(m1, t, bf) * sc;
        ws[WS_W2F + t] = ldp(w2, t, bf);
    }
    if (t == 0) ws[WS_B2F] = ldp(b2, 0, bf);
}

// ---------------- main: stream x, fused 3-layer MLP (f16 dot2), max over depth chunk ----------------
__global__ __launch_bounds__(64, 2) void main_kernel(const void* __restrict__ xv,
                                                     const float* __restrict__ ws,
                                                     float* __restrict__ part)
{
    const unsigned int* wsu = (const unsigned int*)ws;
    bool bf = (wsu[WS_FLAG] != 0u);
    const unsigned int* xb = (const unsigned int*)xv;  // bf16 view: dword = 2 adjacent px of one ch
    const float2*      xf = (const float2*)xv;         // fp32 view: float2 = 2 adjacent px

    int lane = threadIdx.x;
    int bid  = blockIdx.x;
    int tile = bid % NTILES;
    int dc   = bid / NTILES;
    int b    = tile / TILES_PER_B;
    int hwp  = (tile % TILES_PER_B) * 64 + lane;       // pixel-pair index within image
    unsigned bbase = (unsigned)(b * (CDHW/2)) + (unsigned)hwp;   // pair-index base (both views)
    int d0 = dc * DCHUNK;

    // preload packed weights into VGPRs (129 weight dwords + 33 f32)
    unsigned int W0p[64], W1p[64];
    float S0[16], S1[8], W2[8];
    {
        const uint4* q0 = (const uint4*)(wsu + WS_W0P);
        #pragma unroll
        for (int i = 0; i < 16; ++i) { uint4 q = q0[i]; W0p[4*i]=q.x; W0p[4*i+1]=q.y; W0p[4*i+2]=q.z; W0p[4*i+3]=q.w; }
        const uint4* q1 = (const uint4*)(wsu + WS_W1P);
        #pragma unroll
        for (int i = 0; i < 16; ++i) { uint4 q = q1[i]; W1p[4*i]=q.x; W1p[4*i+1]=q.y; W1p[4*i+2]=q.z; W1p[4*i+3]=q.w; }
        const float4* qs = (const float4*)(ws + WS_S0F);
        #pragma unroll
        for (int i = 0; i < 4; ++i) { float4 f = qs[i]; S0[4*i]=f.x; S0[4*i+1]=f.y; S0[4*i+2]=f.z; S0[4*i+3]=f.w; }
        const float4* qt = (const float4*)(ws + WS_S1F);
        #pragma unroll
        for (int i = 0; i < 2; ++i) { float4 f = qt[i]; S1[4*i]=f.x; S1[4*i+1]=f.y; S1[4*i+2]=f.z; S1[4*i+3]=f.w; }
        const float4* qw = (const float4*)(ws + WS_W2F);
        #pragma unroll
        for (int i = 0; i < 2; ++i) { float4 f = qw[i]; W2[4*i]=f.x; W2[4*i+1]=f.y; W2[4*i+2]=f.z; W2[4*i+3]=f.w; }
    }
    float B2v = ws[WS_B2F];

    float mA = -1e30f, mB = -1e30f;

    #pragma unroll 2
    for (int dd = 0; dd < DCHUNK; ++dd) {
        int d = d0 + dd;
        unsigned idx0 = bbase + (unsigned)(d * (HW/2));

        // build per-pixel channel-pair f16x2: xA = even pixel, xB = odd pixel
        unsigned int xA[4], xB[4];
        if (bf) {
            unsigned int xd[8];
            #pragma unroll
            for (int c = 0; c < 8; ++c) xd[c] = xb[idx0 + (unsigned)(c * (DHW/2))];
            #pragma unroll
            for (int j = 0; j < 4; ++j) {
                xA[j] = pkrtz_u(asf(xd[2*j] << 16),        asf(xd[2*j+1] << 16));         // lo halves
                xB[j] = pkrtz_u(asf(xd[2*j] & 0xFFFF0000u), asf(xd[2*j+1] & 0xFFFF0000u)); // hi halves
            }
        } else {
            float2 v[8];
            #pragma unroll
            for (int c = 0; c < 8; ++c) v[c] = xf[idx0 + (unsigned)(c * (DHW/2))];
            #pragma unroll
            for (int j = 0; j < 4; ++j) {
                xA[j] = pkrtz_u(v[2*j].x, v[2*j+1].x);
                xB[j] = pkrtz_u(v[2*j].y, v[2*j+1].y);
            }
        }

        // layer 0: 8 -> 16, folded bias, relu
        float h0A[16], h0B[16];
        #pragma unroll
        for (int o = 0; o < 16; ++o) {
            float a = S0[o], c = S0[o];
            #pragma unroll
            for (int j = 0; j < 4; ++j) {
                a = fdot2_u(xA[j], W0p[o*4 + j], a);
                c = fdot2_u(xB[j], W0p[o*4 + j], c);
            }
            h0A[o] = fmaxf(a, 0.f);
            h0B[o] = fmaxf(c, 0.f);
        }
        unsigned int gA[8], gB[8];
        #pragma unroll
        for (int k = 0; k < 8; ++k) {
            gA[k] = pkrtz_u(h0A[2*k], h0A[2*k+1]);
            gB[k] = pkrtz_u(h0B[2*k], h0B[2*k+1]);
        }

        // layer 1: 16 -> 8 (+relu), layer 2: 8 -> 1 fused
        float sA = B2v, sB = B2v;
        #pragma unroll
        for (int o = 0; o < 8; ++o) {
            float a = S1[o], c = S1[o];
            #pragma unroll
            for (int k = 0; k < 8; ++k) {
                a = fdot2_u(gA[k], W1p[o*8 + k], a);
                c = fdot2_u(gB[k], W1p[o*8 + k], c);
            }
            sA = fmaf(W2[o], fmaxf(a, 0.f), sA);
            sB = fmaf(W2[o], fmaxf(c, 0.f), sB);
        }
        mA = fmaxf(mA, sA);
        mB = fmaxf(mB, sB);
    }

    float2 r; r.x = mA; r.y = mB;
    float2* pp = (float2*)(part + (size_t)dc * NPIX + (size_t)b * HW);
    pp[hwp] = r;   // coalesced 8 B/lane
}

// ---------------- reduce: max over depth chunks, sigmoid, dtype-correct store ----------------
__global__ __launch_bounds__(256) void reduce_kernel(const float* __restrict__ part,
                                                     const float* __restrict__ ws,
                                                     void* __restrict__ out)
{
    bool bf = (((const unsigned int*)ws)[WS_FLAG] != 0u);
    int px = blockIdx.x * 256 + threadIdx.x;
    float m = part[px];
    #pragma unroll
    for (int k = 1; k < DSPLIT; ++k) m = fmaxf(m, part[(size_t)k * NPIX + px]);
    float sg = 1.0f / (1.0f + __expf(-m));   // sigmoid(max) == max(sigmoid): monotone
    if (bf) {
        unsigned int u = asu(sg);
        unsigned int r = (u + 0x7FFFu + ((u >> 16) & 1u)) >> 16;   // RNE bf16 (sg > 0, finite)
        ((unsigned short*)out)[px] = (unsigned short)r;
    } else {
        ((float*)out)[px] = sg;
    }
}

extern "C" void kernel_launch(void* const* d_in, const int* in_sizes, int n_in,
                              void* d_out, int out_size, void* d_ws, size_t ws_size,
                              hipStream_t stream)
{
    float* ws = (float*)d_ws;

    prep_kernel<<<1, 64, 0, stream>>>(
        (const unsigned int*)d_in[0],
        d_in[1], d_in[2], d_in[3], d_in[4], d_in[5], d_in[6],
        d_in[7], d_in[8], d_in[9], d_in[10], d_in[11], d_in[12], ws);

    main_kernel<<<NTILES * DSPLIT, 64, 0, stream>>>(d_in[0], ws, ws + WS_PART);

    reduce_kernel<<<NPIX / 256, 256, 0, stream>>>(ws + WS_PART, ws, d_out);
}